// Round 12
// baseline (175.942 us; speedup 1.0000x reference)
//
#include <hip/hip_runtime.h>
#include <stdint.h>

typedef unsigned int uint32;
typedef unsigned char u8;
typedef int v4i __attribute__((ext_vector_type(4)));

#define BB 64
#define CC 256
#define OO 256
#define HH 28
#define WW 28
#define HWP 784           // 28*28
#define NWT 589824        // 256*256*9
#define WTAP (256 * 256)  // 65,536 B per weight tap panel
#define PPIX 272          // LDS bytes per pixel (256 + 16 pad)

// ---------------------------------------------------------------------------
// Kernel 1: weight sign -> i8 tap panels.  wi8[t][o][c] = sign(M + rv.Z)
// (rsqrt normalizer is positive — proven). Unchanged, verified exact.
// ---------------------------------------------------------------------------
__global__ __launch_bounds__(256) void cast_w_kernel(
    const float* __restrict__ M, const float* __restrict__ Z,
    const float* __restrict__ rv, u8* __restrict__ wi8) {
  __shared__ float sacc[2304];
  const int o = blockIdx.x;
  const int tid = threadIdx.x;
  const size_t base = (size_t)o * 2304;
  float r[8];
#pragma unroll
  for (int k = 0; k < 8; ++k) r[k] = rv[k];
#pragma unroll
  for (int ii = 0; ii < 9; ++ii) {
    int i = tid + ii * 256;  // 2304 = 9*256 exactly
    float s = M[base + i];
#pragma unroll
    for (int k = 0; k < 8; ++k) s += r[k] * Z[(size_t)k * NWT + base + i];
    sacc[i] = s;
  }
  __syncthreads();
  const int c = tid;  // M index i = o*2304 + c*9 + t  (t = kh*3+kw = tap)
#pragma unroll
  for (int t = 0; t < 9; ++t) {
    float s = sacc[c * 9 + t];
    wi8[((size_t)t * 256 + o) * 256 + c] = (s > 0.f) ? (u8)1 : (u8)0xFF;
  }
}

// Load k-group g (tap = g/4, ks = g%4): 7 A-fragments from LDS + 4 B-frags
// from L2. Only invoked from a FULLY-UNROLLED loop -> all static indexing.
#define LOADG(g_, AF, BF)                                                      \
  {                                                                            \
    const int tap_ = (g_) >> 2, ks_ = (g_) & 3;                                \
    const int toff_ =                                                          \
        ((tap_ / 3) * 30 + (tap_ % 3)) * PPIX + ks_ * 64;                      \
    _Pragma("unroll") for (int ot = 0; ot < 4; ++ot)                           \
        (BF)[ot] = *(const v4i*)(Bb + ((size_t)tap_ * WTAP) +                  \
                                 (bvoff + ot * 4096 + ks_ * 64));              \
    _Pragma("unroll") for (int mt = 0; mt < 7; ++mt)                           \
        (AF)[mt] = *(const v4i*)(&albs[lb[mt] + toff_]);                       \
  }

#define MFMAG(AF, BF)                                                          \
  {                                                                            \
    _Pragma("unroll") for (int mt = 0; mt < 7; ++mt)                           \
        _Pragma("unroll") for (int ot = 0; ot < 4; ++ot)                       \
            acc[mt][ot] = __builtin_amdgcn_mfma_i32_16x16x64_i8(               \
                (AF)[mt], (BF)[ot], acc[mt][ot], 0, 0, 0);                     \
  }

#define SGB() __builtin_amdgcn_sched_barrier(0)

// ---------------------------------------------------------------------------
// Kernel 2 (R11): FUSED sign-cast + i8 MFMA implicit-GEMM conv.
//
// R10 post-mortem: 4th scheduling variant null — conv pinned at ~48-50 µs
// across rolled / unrolled / ping-pong / SGB-pinned schedules, and both
// occupancy directions lose (R9: +waves -> LDS-pipe saturated; 1 wave/SIMD
// -> MFMA issue serialization). Conv is structurally plateaued; the
// remaining clean cut is the PIPELINE AROUND it: cast_x was a full extra
// pass over x (82 MB read + 14.7 MB xi8 write) whose output conv's staging
// consumed exactly once (12.6 MB re-read). Fused here: each block stages
// sign(x) for its 6 padded rows (30 px x 256 c) straight into LDS.
//   - deletes the cast_x dispatch + 97 MB of its traffic + conv's re-read
//   - adds 1.5x-halo f32 reads (~123 MB total, hidden: conv ran at 16% HBM)
//     and ~1.5K cy/block of sign-pack VALU (vs 65K cy block makespan)
// Staging predicate/pack = cast_x's verified logic inlined; padded-row
// indexing: local row r (0..5) <-> padded row h0+r <-> image row h0+r-1,
// matching the lb[] map ((h - h0)*30 + w, h = image row of output pixel).
// K-loop, B-panel reads, epilogue C/D map byte-identical to R10
// (absmax 0.0, verified R4-R10).
// ---------------------------------------------------------------------------
__global__ __launch_bounds__(256, 2) void conv_mfma_kernel(
    const float* __restrict__ x, const u8* __restrict__ wi8,
    const float* __restrict__ alpha, float* __restrict__ out) {
  __shared__ u8 albs[6 * 30 * PPIX];  // 48,960 B
  const int tid = threadIdx.x;
  const int lane = tid & 63;
  const int wv = tid >> 6;         // wave 0..3 -> o-quarter
  const int l15 = lane & 15;
  const int lk  = lane >> 4;       // 0..3
  const int pixb = blockIdx.x * 112;
  const int h0   = blockIdx.x * 4;  // first output image row of this block
  const int b    = blockIdx.y;

  // Fused staging: albs[(r*30+wp)*PPIX + c] = sign(x[b][c][h0+r-1][wp-1]),
  // zero outside the image (conv zero-pad). 6 rows x 30 wp x 256 c.
  {
    const int wp = tid & 31;         // 0..31 (30,31 idle)
    const int rseg = tid >> 5;       // 0..7 (6,7 idle)
    if (rseg < 6 && wp < 30) {
      const int imgrow = h0 + rseg - 1;
      const bool rowok = (imgrow >= 0) && (imgrow < HH);
      const bool interior = rowok && (wp >= 1) && (wp <= WW);
      const float* xp =
          x + ((size_t)(b * CC) * HH + (rowok ? imgrow : 0)) * WW + (wp - 1);
      u8* dst = &albs[(rseg * 30 + wp) * PPIX];
#pragma unroll
      for (int c4 = 0; c4 < 16; ++c4) {   // 4 c-quads -> one 16B LDS write
        uint32 vv[4];
#pragma unroll
        for (int q = 0; q < 4; ++q) {
          const int cq = c4 * 4 + q;      // c-quad 0..63
          uint32 v = 0;
          if (interior) {
            const float* p = xp + (size_t)(cq * 4) * HWP;
            uint32 b0 = (p[0] > 0.f) ? 0x01u : 0xFFu;
            uint32 b1 = (p[HWP] > 0.f) ? 0x01u : 0xFFu;
            uint32 b2 = (p[2 * HWP] > 0.f) ? 0x01u : 0xFFu;
            uint32 b3 = (p[3 * HWP] > 0.f) ? 0x01u : 0xFFu;
            v = b0 | (b1 << 8) | (b2 << 16) | (b3 << 24);
          }
          vv[q] = v;
        }
        *(uint4*)(dst + c4 * 16) = make_uint4(vv[0], vv[1], vv[2], vv[3]);
      }
    }
  }
  __syncthreads();

  // Per-lane LDS base for the 7 m-tiles at tap (0,0); taps add constants.
  int lb[7];
#pragma unroll
  for (int mt = 0; mt < 7; ++mt) {
    int p = pixb + mt * 16 + l15;        // output pixel of this A-row
    int h = p / 28, w = p - h * 28;
    lb[mt] = ((h - h0) * 30 + w) * PPIX + lk * 16;  // tap(0,0) input px
  }
  const u8* Bb = wi8 + wv * (64 * 256);
  const int bvoff = l15 * 256 + lk * 16;

  float aval[4];
#pragma unroll
  for (int ot = 0; ot < 4; ++ot) aval[ot] = alpha[wv * 64 + ot * 16 + l15];

  v4i acc[7][4];
#pragma unroll
  for (int mt = 0; mt < 7; ++mt)
#pragma unroll
    for (int ot = 0; ot < 4; ++ot) acc[mt][ot] = v4i{0, 0, 0, 0};

  // 36 k-groups (9 taps x 4 ks), depth-1 ping-pong, fence-pinned schedule.
  v4i A0[7], B0[4], A1[7], B1[4];
  LOADG(0, A0, B0);
#pragma unroll
  for (int g = 0; g < 36; g += 2) {
    LOADG(g + 1, A1, B1);          // prefetch odd group
    SGB();                         // loads may not sink below this point
    MFMAG(A0, B0);                 // ~574 cy shadow over the prefetch
    SGB();
    if (g + 2 < 36) LOADG(g + 2, A0, B0);  // prefetch next even group
    SGB();
    MFMAG(A1, B1);
    SGB();
  }

  // Epilogue: C/D map col=lane&15 (o), row=(lane>>4)*4+reg (pixel). float4
  // stores, 16B aligned (prow % 4 == 0). Verified exact in R4-R10.
#pragma unroll
  for (int mt = 0; mt < 7; ++mt) {
    const int prow = pixb + mt * 16 + lk * 4;
#pragma unroll
    for (int ot = 0; ot < 4; ++ot) {
      float* op = out +
          ((size_t)b * 256 + (wv * 64 + ot * 16 + l15)) * HWP + prow;
      float4 vst;
      vst.x = aval[ot] * (float)acc[mt][ot][0];
      vst.y = aval[ot] * (float)acc[mt][ot][1];
      vst.z = aval[ot] * (float)acc[mt][ot][2];
      vst.w = aval[ot] * (float)acc[mt][ot][3];
      *(float4*)op = vst;
    }
  }
}

// ---------------------------------------------------------------------------
extern "C" void kernel_launch(void* const* d_in, const int* in_sizes, int n_in,
                              void* d_out, int out_size, void* d_ws,
                              size_t ws_size, hipStream_t stream) {
  const float* x     = (const float*)d_in[0];  // (64,256,28,28)
  const float* M     = (const float*)d_in[1];  // (256,256,3,3)
  const float* Z     = (const float*)d_in[2];  // (8,256,256,3,3)
  const float* alpha = (const float*)d_in[3];  // (256,1,1)
  const float* rv    = (const float*)d_in[4];  // (1,8)
  float* out = (float*)d_out;                  // (64,256,28,28)

  u8* wi8 = (u8*)d_ws;                         // 589,824 B tap panels

  cast_w_kernel<<<dim3(256), 256, 0, stream>>>(M, Z, rv, wi8);
  conv_mfma_kernel<<<dim3(7, BB), 256, 0, stream>>>(x, wi8, alpha, out);
}

// Round 13
// 161.954 us; speedup vs baseline: 1.0864x; 1.0864x over previous
//
#include <hip/hip_runtime.h>
#include <stdint.h>

typedef unsigned int uint32;
typedef unsigned char u8;
typedef int v4i __attribute__((ext_vector_type(4)));

#define BB 64
#define CC 256
#define OO 256
#define HH 28
#define WW 28
#define HWP 784           // 28*28
#define NWT 589824        // 256*256*9
#define HP 30             // padded spatial (1-px halo each side)
#define XBSTR (HP * HP * 256)   // 230,400 B per padded batch image
#define WTAP (256 * 256)  // 65,536 B per weight tap panel
#define PPIX 272          // LDS bytes per pixel (256 + 16 pad)

// ---------------------------------------------------------------------------
// Kernel 1 (R13): MERGED prep — cast_w (blocks 0..255) + cast_x (256..2175).
// The two passes are data-independent; R10 ran them as serial dispatches
// (~15 + ~5 µs). Merged, cast_w's 21 MB overlaps under cast_x's 97 MB
// stream and one launch gap disappears. cast_w blocks go FIRST so the
// 256-block long pole starts immediately. Bodies are the R5/R10-verified
// code, unchanged; LDS is a 9216 B union.
// ---------------------------------------------------------------------------
__global__ __launch_bounds__(256) void prep_kernel(
    const float* __restrict__ x, const float* __restrict__ M,
    const float* __restrict__ Z, const float* __restrict__ rv,
    u8* __restrict__ xi8, u8* __restrict__ wi8) {
  __shared__ float smem[2304];   // 9216 B; cast_x aliases first 7800 B
  const int bx = blockIdx.x;
  const int tid = threadIdx.x;

  if (bx < 256) {
    // ---- cast_w: wi8[t][o][c] = sign(M + rv.Z) (verified exact) ----
    const int o = bx;
    const size_t base = (size_t)o * 2304;
    float r[8];
#pragma unroll
    for (int k = 0; k < 8; ++k) r[k] = rv[k];
#pragma unroll
    for (int ii = 0; ii < 9; ++ii) {
      int i = tid + ii * 256;  // 2304 = 9*256 exactly
      float s = M[base + i];
#pragma unroll
      for (int k = 0; k < 8; ++k) s += r[k] * Z[(size_t)k * NWT + base + i];
      smem[i] = s;
    }
    __syncthreads();
    const int c = tid;  // M index i = o*2304 + c*9 + t  (t = kh*3+kw)
#pragma unroll
    for (int t = 0; t < 9; ++t) {
      float s = smem[c * 9 + t];
      wi8[((size_t)t * 256 + o) * 256 + c] = (s > 0.f) ? (u8)1 : (u8)0xFF;
    }
  } else {
    // ---- cast_x: xi8[b][hp][wp][c] = sign(x), border rows/cols = 0 ----
    u8* srow = (u8*)smem;            // 30*260 = 7800 B
    const int bxi = bx - 256;
    const int hp = bxi % 30;
    const int b  = bxi / 30;
    const int wp = tid & 31;         // 0..31 (30,31 idle on compute)
    const int cq0 = tid >> 5;        // 0..7
    const bool interior = (hp >= 1) && (hp <= 28) && (wp >= 1) && (wp <= 28);
    const float* xp =
        x + (((size_t)b * 256) * 28 + (hp - 1)) * 28 + (wp - 1);  // + c*784
    if (wp < HP) {
#pragma unroll
      for (int it = 0; it < 8; ++it) {
        const int cq = it * 8 + cq0;   // c-quad 0..63
        uint32 v = 0;
        if (interior) {
          const float* p = xp + (size_t)(cq * 4) * HWP;
          uint32 b0 = (p[0] > 0.f) ? 0x01u : 0xFFu;
          uint32 b1 = (p[HWP] > 0.f) ? 0x01u : 0xFFu;
          uint32 b2 = (p[2 * HWP] > 0.f) ? 0x01u : 0xFFu;
          uint32 b3 = (p[3 * HWP] > 0.f) ? 0x01u : 0xFFu;
          v = b0 | (b1 << 8) | (b2 << 16) | (b3 << 24);
        }
        *(uint32*)(&srow[wp * 260 + cq * 4]) = v;
      }
    }
    __syncthreads();
    u8* rowbase = xi8 + (size_t)b * XBSTR + (size_t)hp * 7680;
#pragma unroll
    for (int i = 0; i < 2; ++i) {
      int c = tid + i * 256;           // 16B chunk id, 0..479
      if (c < 480) {
        uint4 v = *(const uint4*)(&srow[(c >> 4) * 260 + (c & 15) * 16]);
        *(uint4*)(rowbase + (size_t)c * 16) = v;
      }
    }
  }
}

// Load k-group g (tap = g/4, ks = g%4): 7 A-fragments from LDS + 4 B-frags
// from L2. Only invoked from a FULLY-UNROLLED loop -> all static indexing.
#define LOADG(g_, AF, BF)                                                      \
  {                                                                            \
    const int tap_ = (g_) >> 2, ks_ = (g_) & 3;                                \
    const int toff_ =                                                          \
        ((tap_ / 3) * 30 + (tap_ % 3)) * PPIX + ks_ * 64;                      \
    _Pragma("unroll") for (int ot = 0; ot < 4; ++ot)                           \
        (BF)[ot] = *(const v4i*)(Bb + ((size_t)tap_ * WTAP) +                  \
                                 (bvoff + ot * 4096 + ks_ * 64));              \
    _Pragma("unroll") for (int mt = 0; mt < 7; ++mt)                           \
        (AF)[mt] = *(const v4i*)(&albs[lb[mt] + toff_]);                       \
  }

#define MFMAG(AF, BF)                                                          \
  {                                                                            \
    __builtin_amdgcn_s_setprio(1);                                             \
    _Pragma("unroll") for (int mt = 0; mt < 7; ++mt)                           \
        _Pragma("unroll") for (int ot = 0; ot < 4; ++ot)                       \
            acc[mt][ot] = __builtin_amdgcn_mfma_i32_16x16x64_i8(               \
                (AF)[mt], (BF)[ot], acc[mt][ot], 0, 0, 0);                     \
    __builtin_amdgcn_s_setprio(0);                                             \
  }

#define SGB() __builtin_amdgcn_sched_barrier(0)

// ---------------------------------------------------------------------------
// Kernel 2 (R13): i8 MFMA implicit-GEMM conv — R10 structure (best measured:
// 47.9-49.4 µs), reverted from the R12 fusion regression (80.7 µs: staging
// x in-block had 4x less TLP than the standalone 1920-block cast_x pass).
// One addition: s_setprio(1) around MFMA clusters (T5). Conv's waves are
// NOT barrier-locked in the k-loop (independent blocks/waves after the one
// staging barrier) — the regime where setprio measured +4-7% (attn, m191),
// not the lockstep-GEMM null (m190).
//
// Ledger: 5 scheduling/structural variants (rolled / unrolled / ping-pong /
// SGB-pinned / 32-o TLP) pinned conv at ~48-62 µs; per-CU cycle audit shows
// pipe-times summing to ~makespan (no inter-pipe overlap). Structural
// plateau for this decomposition; R10 config is the best point.
// Data layouts, staging, epilogue C/D map verified exact R4-R12.
// ---------------------------------------------------------------------------
__global__ __launch_bounds__(256, 2) void conv_mfma_kernel(
    const u8* __restrict__ xi8, const u8* __restrict__ wi8,
    const float* __restrict__ alpha, float* __restrict__ out) {
  __shared__ u8 albs[6 * 30 * PPIX];  // 48,960 B
  const int tid = threadIdx.x;
  const int lane = tid & 63;
  const int wv = tid >> 6;         // wave 0..3 -> o-quarter
  const int l15 = lane & 15;
  const int lk  = lane >> 4;       // 0..3
  const int pixb = blockIdx.x * 112;
  const int h0   = blockIdx.x * 4;  // first output image row of this block
  const int b    = blockIdx.y;

  // Stage 6 padded rows (2880 x 16B chunks) global->LDS, 272B pixel stride.
  {
    const u8* gsrc = xi8 + (size_t)b * XBSTR + (size_t)h0 * 7680;
#pragma unroll
    for (int i = 0; i < 12; ++i) {
      int c = tid + i * 256;
      if (c < 2880) {
        uint4 v = *(const uint4*)(gsrc + (size_t)c * 16);
        *(uint4*)(&albs[(c >> 4) * PPIX + (c & 15) * 16]) = v;
      }
    }
  }
  __syncthreads();

  // Per-lane LDS base for the 7 m-tiles at tap (0,0); taps add constants.
  int lb[7];
#pragma unroll
  for (int mt = 0; mt < 7; ++mt) {
    int p = pixb + mt * 16 + l15;        // output pixel of this A-row
    int h = p / 28, w = p - h * 28;
    lb[mt] = ((h - h0) * 30 + w) * PPIX + lk * 16;  // tap(0,0) input px
  }
  const u8* Bb = wi8 + wv * (64 * 256);
  const int bvoff = l15 * 256 + lk * 16;

  float aval[4];
#pragma unroll
  for (int ot = 0; ot < 4; ++ot) aval[ot] = alpha[wv * 64 + ot * 16 + l15];

  v4i acc[7][4];
#pragma unroll
  for (int mt = 0; mt < 7; ++mt)
#pragma unroll
    for (int ot = 0; ot < 4; ++ot) acc[mt][ot] = v4i{0, 0, 0, 0};

  // 36 k-groups (9 taps x 4 ks), depth-1 ping-pong, fence-pinned schedule.
  v4i A0[7], B0[4], A1[7], B1[4];
  LOADG(0, A0, B0);
#pragma unroll
  for (int g = 0; g < 36; g += 2) {
    LOADG(g + 1, A1, B1);          // prefetch odd group
    SGB();                         // loads may not sink below this point
    MFMAG(A0, B0);                 // ~574 cy shadow over the prefetch
    SGB();
    if (g + 2 < 36) LOADG(g + 2, A0, B0);  // prefetch next even group
    SGB();
    MFMAG(A1, B1);
    SGB();
  }

  // Epilogue: C/D map col=lane&15 (o), row=(lane>>4)*4+reg (pixel). float4
  // stores, 16B aligned (prow % 4 == 0). Verified exact in R4-R12.
#pragma unroll
  for (int mt = 0; mt < 7; ++mt) {
    const int prow = pixb + mt * 16 + lk * 4;
#pragma unroll
    for (int ot = 0; ot < 4; ++ot) {
      float* op = out +
          ((size_t)b * 256 + (wv * 64 + ot * 16 + l15)) * HWP + prow;
      float4 vst;
      vst.x = aval[ot] * (float)acc[mt][ot][0];
      vst.y = aval[ot] * (float)acc[mt][ot][1];
      vst.z = aval[ot] * (float)acc[mt][ot][2];
      vst.w = aval[ot] * (float)acc[mt][ot][3];
      *(float4*)op = vst;
    }
  }
}

// ---------------------------------------------------------------------------
extern "C" void kernel_launch(void* const* d_in, const int* in_sizes, int n_in,
                              void* d_out, int out_size, void* d_ws,
                              size_t ws_size, hipStream_t stream) {
  const float* x     = (const float*)d_in[0];  // (64,256,28,28)
  const float* M     = (const float*)d_in[1];  // (256,256,3,3)
  const float* Z     = (const float*)d_in[2];  // (8,256,256,3,3)
  const float* alpha = (const float*)d_in[3];  // (256,1,1)
  const float* rv    = (const float*)d_in[4];  // (1,8)
  float* out = (float*)d_out;                  // (64,256,28,28)

  u8* xi8 = (u8*)d_ws;                          // 14,745,600 B padded NHWC
  u8* wi8 = (u8*)d_ws + 14745600;               // 589,824 B tap panels

  prep_kernel<<<dim3(256 + HP * BB), 256, 0, stream>>>(x, M, Z, rv, xi8, wi8);
  conv_mfma_kernel<<<dim3(7, BB), 256, 0, stream>>>(xi8, wi8, alpha, out);
}

// Round 14
// 161.344 us; speedup vs baseline: 1.0905x; 1.0038x over previous
//
#include <hip/hip_runtime.h>
#include <stdint.h>

typedef unsigned int uint32;
typedef unsigned char u8;
typedef int v4i __attribute__((ext_vector_type(4)));

#define BB 64
#define CC 256
#define OO 256
#define HH 28
#define WW 28
#define HWP 784           // 28*28
#define NWT 589824        // 256*256*9
#define HP 30             // padded spatial (1-px halo each side)
#define XBSTR (HP * HP * 256)   // 230,400 B per padded batch image
#define WTAP (256 * 256)  // 65,536 B per weight tap panel
#define PPIX 272          // LDS bytes per pixel (256 + 16 pad)

// ---------------------------------------------------------------------------
// Kernel 1 (R13, kept): MERGED prep — cast_w (blocks 0..255) + cast_x
// (256..2175). Confirmed WIN (~7-8 µs): cast_w's 21 MB overlaps under
// cast_x's 97 MB stream, one dispatch gap gone. Bodies unchanged/verified.
// ---------------------------------------------------------------------------
__global__ __launch_bounds__(256) void prep_kernel(
    const float* __restrict__ x, const float* __restrict__ M,
    const float* __restrict__ Z, const float* __restrict__ rv,
    u8* __restrict__ xi8, u8* __restrict__ wi8) {
  __shared__ float smem[2304];   // 9216 B; cast_x aliases first 7800 B
  const int bx = blockIdx.x;
  const int tid = threadIdx.x;

  if (bx < 256) {
    // ---- cast_w: wi8[t][o][c] = sign(M + rv.Z) (verified exact) ----
    const int o = bx;
    const size_t base = (size_t)o * 2304;
    float r[8];
#pragma unroll
    for (int k = 0; k < 8; ++k) r[k] = rv[k];
#pragma unroll
    for (int ii = 0; ii < 9; ++ii) {
      int i = tid + ii * 256;  // 2304 = 9*256 exactly
      float s = M[base + i];
#pragma unroll
      for (int k = 0; k < 8; ++k) s += r[k] * Z[(size_t)k * NWT + base + i];
      smem[i] = s;
    }
    __syncthreads();
    const int c = tid;  // M index i = o*2304 + c*9 + t  (t = kh*3+kw)
#pragma unroll
    for (int t = 0; t < 9; ++t) {
      float s = smem[c * 9 + t];
      wi8[((size_t)t * 256 + o) * 256 + c] = (s > 0.f) ? (u8)1 : (u8)0xFF;
    }
  } else {
    // ---- cast_x: xi8[b][hp][wp][c] = sign(x), border rows/cols = 0 ----
    u8* srow = (u8*)smem;            // 30*260 = 7800 B
    const int bxi = bx - 256;
    const int hp = bxi % 30;
    const int b  = bxi / 30;
    const int wp = tid & 31;         // 0..31 (30,31 idle on compute)
    const int cq0 = tid >> 5;        // 0..7
    const bool interior = (hp >= 1) && (hp <= 28) && (wp >= 1) && (wp <= 28);
    const float* xp =
        x + (((size_t)b * 256) * 28 + (hp - 1)) * 28 + (wp - 1);  // + c*784
    if (wp < HP) {
#pragma unroll
      for (int it = 0; it < 8; ++it) {
        const int cq = it * 8 + cq0;   // c-quad 0..63
        uint32 v = 0;
        if (interior) {
          const float* p = xp + (size_t)(cq * 4) * HWP;
          uint32 b0 = (p[0] > 0.f) ? 0x01u : 0xFFu;
          uint32 b1 = (p[HWP] > 0.f) ? 0x01u : 0xFFu;
          uint32 b2 = (p[2 * HWP] > 0.f) ? 0x01u : 0xFFu;
          uint32 b3 = (p[3 * HWP] > 0.f) ? 0x01u : 0xFFu;
          v = b0 | (b1 << 8) | (b2 << 16) | (b3 << 24);
        }
        *(uint32*)(&srow[wp * 260 + cq * 4]) = v;
      }
    }
    __syncthreads();
    u8* rowbase = xi8 + (size_t)b * XBSTR + (size_t)hp * 7680;
#pragma unroll
    for (int i = 0; i < 2; ++i) {
      int c = tid + i * 256;           // 16B chunk id, 0..479
      if (c < 480) {
        uint4 v = *(const uint4*)(&srow[(c >> 4) * 260 + (c & 15) * 16]);
        *(uint4*)(rowbase + (size_t)c * 16) = v;
      }
    }
  }
}

// Load k-group g (tap = g/4, ks = g%4): 7 A-fragments from LDS + 4 B-frags
// from L2. Only invoked from a FULLY-UNROLLED loop -> all static indexing.
#define LOADG(g_, AF, BF)                                                      \
  {                                                                            \
    const int tap_ = (g_) >> 2, ks_ = (g_) & 3;                                \
    const int toff_ =                                                          \
        ((tap_ / 3) * 30 + (tap_ % 3)) * PPIX + ks_ * 64;                      \
    _Pragma("unroll") for (int ot = 0; ot < 4; ++ot)                           \
        (BF)[ot] = *(const v4i*)(Bb + ((size_t)tap_ * WTAP) +                  \
                                 (bvoff + ot * 4096 + ks_ * 64));              \
    _Pragma("unroll") for (int mt = 0; mt < 7; ++mt)                           \
        (AF)[mt] = *(const v4i*)(&albs[lb[mt] + toff_]);                       \
  }

// R14: setprio REMOVED (R13 A/B: conv 48->54.5 µs with it — m190's
// GEMM-negative regime, not m191's attn-positive; boosting the MFMA wave
// starves the co-resident wave's LOADG issue that provided the only
// inter-wave overlap).
#define MFMAG(AF, BF)                                                          \
  {                                                                            \
    _Pragma("unroll") for (int mt = 0; mt < 7; ++mt)                           \
        _Pragma("unroll") for (int ot = 0; ot < 4; ++ot)                       \
            acc[mt][ot] = __builtin_amdgcn_mfma_i32_16x16x64_i8(               \
                (AF)[mt], (BF)[ot], acc[mt][ot], 0, 0, 0);                     \
  }

#define SGB() __builtin_amdgcn_sched_barrier(0)

// ---------------------------------------------------------------------------
// Kernel 2 (R14 = R10 conv, the measured best at 47.9-49.4 µs):
// i8 MFMA implicit-GEMM conv, LDS-staged A, SGB-pinned ping-pong k-loop.
//
// Ledger: 5 scheduling/structural variants (rolled / unrolled / ping-pong /
// SGB-pinned / 32-o TLP) pinned conv at ~48-62 µs; both occupancy
// directions lose; setprio loses (R13). Structural plateau at ~31% of the
// i8 MFMA ceiling for this decomposition. Layouts/epilogue verified exact
// (absmax 0.0, R4-R13).
// ---------------------------------------------------------------------------
__global__ __launch_bounds__(256, 2) void conv_mfma_kernel(
    const u8* __restrict__ xi8, const u8* __restrict__ wi8,
    const float* __restrict__ alpha, float* __restrict__ out) {
  __shared__ u8 albs[6 * 30 * PPIX];  // 48,960 B
  const int tid = threadIdx.x;
  const int lane = tid & 63;
  const int wv = tid >> 6;         // wave 0..3 -> o-quarter
  const int l15 = lane & 15;
  const int lk  = lane >> 4;       // 0..3
  const int pixb = blockIdx.x * 112;
  const int h0   = blockIdx.x * 4;  // first output image row of this block
  const int b    = blockIdx.y;

  // Stage 6 padded rows (2880 x 16B chunks) global->LDS, 272B pixel stride.
  {
    const u8* gsrc = xi8 + (size_t)b * XBSTR + (size_t)h0 * 7680;
#pragma unroll
    for (int i = 0; i < 12; ++i) {
      int c = tid + i * 256;
      if (c < 2880) {
        uint4 v = *(const uint4*)(gsrc + (size_t)c * 16);
        *(uint4*)(&albs[(c >> 4) * PPIX + (c & 15) * 16]) = v;
      }
    }
  }
  __syncthreads();

  // Per-lane LDS base for the 7 m-tiles at tap (0,0); taps add constants.
  int lb[7];
#pragma unroll
  for (int mt = 0; mt < 7; ++mt) {
    int p = pixb + mt * 16 + l15;        // output pixel of this A-row
    int h = p / 28, w = p - h * 28;
    lb[mt] = ((h - h0) * 30 + w) * PPIX + lk * 16;  // tap(0,0) input px
  }
  const u8* Bb = wi8 + wv * (64 * 256);
  const int bvoff = l15 * 256 + lk * 16;

  float aval[4];
#pragma unroll
  for (int ot = 0; ot < 4; ++ot) aval[ot] = alpha[wv * 64 + ot * 16 + l15];

  v4i acc[7][4];
#pragma unroll
  for (int mt = 0; mt < 7; ++mt)
#pragma unroll
    for (int ot = 0; ot < 4; ++ot) acc[mt][ot] = v4i{0, 0, 0, 0};

  // 36 k-groups (9 taps x 4 ks), depth-1 ping-pong, fence-pinned schedule.
  v4i A0[7], B0[4], A1[7], B1[4];
  LOADG(0, A0, B0);
#pragma unroll
  for (int g = 0; g < 36; g += 2) {
    LOADG(g + 1, A1, B1);          // prefetch odd group
    SGB();                         // loads may not sink below this point
    MFMAG(A0, B0);                 // ~574 cy shadow over the prefetch
    SGB();
    if (g + 2 < 36) LOADG(g + 2, A0, B0);  // prefetch next even group
    SGB();
    MFMAG(A1, B1);
    SGB();
  }

  // Epilogue: C/D map col=lane&15 (o), row=(lane>>4)*4+reg (pixel). float4
  // stores, 16B aligned (prow % 4 == 0). Verified exact in R4-R13.
#pragma unroll
  for (int mt = 0; mt < 7; ++mt) {
    const int prow = pixb + mt * 16 + lk * 4;
#pragma unroll
    for (int ot = 0; ot < 4; ++ot) {
      float* op = out +
          ((size_t)b * 256 + (wv * 64 + ot * 16 + l15)) * HWP + prow;
      float4 vst;
      vst.x = aval[ot] * (float)acc[mt][ot][0];
      vst.y = aval[ot] * (float)acc[mt][ot][1];
      vst.z = aval[ot] * (float)acc[mt][ot][2];
      vst.w = aval[ot] * (float)acc[mt][ot][3];
      *(float4*)op = vst;
    }
  }
}

// ---------------------------------------------------------------------------
extern "C" void kernel_launch(void* const* d_in, const int* in_sizes, int n_in,
                              void* d_out, int out_size, void* d_ws,
                              size_t ws_size, hipStream_t stream) {
  const float* x     = (const float*)d_in[0];  // (64,256,28,28)
  const float* M     = (const float*)d_in[1];  // (256,256,3,3)
  const float* Z     = (const float*)d_in[2];  // (8,256,256,3,3)
  const float* alpha = (const float*)d_in[3];  // (256,1,1)
  const float* rv    = (const float*)d_in[4];  // (1,8)
  float* out = (float*)d_out;                  // (64,256,28,28)

  u8* xi8 = (u8*)d_ws;                          // 14,745,600 B padded NHWC
  u8* wi8 = (u8*)d_ws + 14745600;               // 589,824 B tap panels

  prep_kernel<<<dim3(256 + HP * BB), 256, 0, stream>>>(x, M, Z, rv, xi8, wi8);
  conv_mfma_kernel<<<dim3(7, BB), 256, 0, stream>>>(xi8, wi8, alpha, out);
}